// Round 1
// baseline (582.492 us; speedup 1.0000x reference)
//
#include <hip/hip_runtime.h>

// SpikingConv2D: tj [16,258,258] f32, kernel [128,1,3,3] f32 (used as flat 9x128),
// D_i [9,128] f32 (only row 0 used). Output [16*256*256, 128] f32 at flat index
// n*128+f with n = (i*256+j)*16+b. Write-BW bound: 512 MB output.

#define B_N   16
#define S_N   258
#define HV_N  256
#define F_N   128

__global__ __launch_bounds__(256, 4) void spiking_conv2d_kernel(
    const float* __restrict__ tj, const float* __restrict__ kern,
    const float* __restrict__ Di, float* __restrict__ out, int num_groups) {
  const int fq   = threadIdx.x & 31;  // filter quad: f = fq*4 .. fq*4+3
  const int nsub = threadIdx.x >> 5;  // 0..7: row within group of 8

  // Per-thread weight columns: W[t][f] = kern_flat[t*128 + f]  (raw view(9,128))
  float4 w[9];
#pragma unroll
  for (int t = 0; t < 9; ++t)
    w[t] = reinterpret_cast<const float4*>(kern)[t * (F_N / 4) + fq];
  const float4 d = reinterpret_cast<const float4*>(Di)[fq];  // D_i[0, 4fq..4fq+3]
  const float4 thr = make_float4(1.0f - d.x, 1.0f - d.y, 1.0f - d.z, 1.0f - d.w);

  for (int g = blockIdx.x; g < num_groups; g += gridDim.x) {
    const int n   = g * 8 + nsub;        // row id: n = (i*256+j)*16 + b
    const int b   = n & (B_N - 1);
    const int pix = n >> 4;
    const int j   = pix & (HV_N - 1);
    const int i   = pix >> 8;

    const float* base = tj + ((long)b * S_N + i) * S_N + j;
    float x[9];
#pragma unroll
    for (int ki = 0; ki < 3; ++ki)
#pragma unroll
      for (int kj = 0; kj < 3; ++kj)
        x[ki * 3 + kj] = base[ki * S_N + kj];  // broadcast across 32 lanes

    float4 acc = thr;
#pragma unroll
    for (int t = 0; t < 9; ++t) {
      acc.x = fmaf(x[t], w[t].x, acc.x);
      acc.y = fmaf(x[t], w[t].y, acc.y);
      acc.z = fmaf(x[t], w[t].z, acc.z);
      acc.w = fmaf(x[t], w[t].w, acc.w);
    }
    acc.x = fminf(acc.x, 1.0f);
    acc.y = fminf(acc.y, 1.0f);
    acc.z = fminf(acc.z, 1.0f);
    acc.w = fminf(acc.w, 1.0f);

    // out flat = n*128 + fq*4 -> float4 index n*32 + fq. Wave writes 1 KB contiguous.
    reinterpret_cast<float4*>(out)[(long)n * (F_N / 4) + fq] = acc;
  }
}

extern "C" void kernel_launch(void* const* d_in, const int* in_sizes, int n_in,
                              void* d_out, int out_size, void* d_ws, size_t ws_size,
                              hipStream_t stream) {
  const float* tj   = (const float*)d_in[0];  // 16*258*258
  const float* kern = (const float*)d_in[1];  // 128*1*3*3 = 1152
  const float* Di   = (const float*)d_in[2];  // 9*128
  float* out = (float*)d_out;                 // 16*256*256*128

  const int num_groups = (HV_N * HV_N * B_N) / 8;  // 131072 groups of 8 rows
  const int grid = 4096;                           // grid-stride, 32 iters/block
  spiking_conv2d_kernel<<<grid, 256, 0, stream>>>(tj, kern, Di, out, num_groups);
}